// Round 13
// baseline (504.696 us; speedup 1.0000x reference)
//
#include <hip/hip_runtime.h>
#include <math.h>

#define NQ 100
#define MM 400
#define DD 512
#define KK 10
#define NS 20           // screened candidates per row (true top-10 must be subset)

typedef short v8s __attribute__((ext_vector_type(8)));   // 8 bf16 (4 VGPRs)
typedef float v4f __attribute__((ext_vector_type(4)));   // 4 f32 acc

// ---- NEW-path workspace byte offsets ----
#define NOFF_S     81920000UL
#define NOFF_XB   145920000UL
#define NOFF_IDX  186880000UL
#define NOFF_VALS 190080000UL
#define NOFF_I10  193280000UL
#define NOFF_RES  194880000UL
#define NEED_NEW  195200000UL

// ---- OLD-path (fallback) offsets ----
#define OOFF_IDX16 81920000UL
#define OOFF_VALSD 84480000UL
#define OOFF_IDX10 87680000UL
#define OOFF_RESD  89280000UL

static __device__ __forceinline__ unsigned short f2bf(float x) {
  unsigned u = __float_as_uint(x);
  unsigned r = (u + 0x7FFFu + ((u >> 16) & 1u)) >> 16;   // RNE; inputs have no NaN
  return (unsigned short)r;
}

// ---------------------------------------------------------------------------
// K1: gather Xs[q][m][:] = X[ranks[m][q]][:]  (f32) + bf16 copy for MFMA screen
// ---------------------------------------------------------------------------
__global__ void k_gather(const float* __restrict__ X, const int* __restrict__ ranks,
                         float* __restrict__ Xs, unsigned short* __restrict__ Xsb,
                         int make_bf) {
  int gid = blockIdx.x * 256 + threadIdx.x;        // 5,120,000 threads exactly
  int c4  = gid & 127;
  int row = gid >> 7;                              // q*MM + m
  int q   = row / MM;
  int m   = row - q * MM;
  int id  = ranks[m * NQ + q];
  float4 v = ((const float4*)X)[(size_t)id * 128 + c4];
  ((float4*)Xs)[(size_t)row * 128 + c4] = v;
  if (make_bf) {
    ushort4 h;
    h.x = f2bf(v.x); h.y = f2bf(v.y); h.z = f2bf(v.z); h.w = f2bf(v.w);
    ((ushort4*)Xsb)[(size_t)row * 128 + c4] = h;
  }
}

// ---------------------------------------------------------------------------
// K2: bf16 MFMA screening GEMM  S = Xs Xs^T per query, S materialized f32.
// ---------------------------------------------------------------------------
#define LDB 40
__launch_bounds__(256)
__global__ void k_gemm(const unsigned short* __restrict__ Xsb, float* __restrict__ S) {
  __shared__ unsigned short As[128 * LDB];
  __shared__ unsigned short Bs[128 * LDB];

  const int q    = blockIdx.y;
  const int mt   = blockIdx.x >> 2;
  const int nt   = blockIdx.x & 3;
  const int m0   = mt * 128, n0 = nt * 128;
  const int tid  = threadIdx.x;
  const int wave = tid >> 6, lane = tid & 63;
  const int wr   = wave >> 1, wc = wave & 1;       // wave origin in block tile
  const int frow = lane & 15, quad = lane >> 4;

  const unsigned short* Xq = Xsb + (size_t)q * MM * DD;

  v4f acc[4][4];
  #pragma unroll
  for (int i = 0; i < 4; ++i)
    #pragma unroll
    for (int j = 0; j < 4; ++j)
      acc[i][j] = (v4f){0.f, 0.f, 0.f, 0.f};

  const int sr = tid >> 1;                 // staging row 0..127
  const int sk = (tid & 1) * 16;           // staging k-half

  for (int kc = 0; kc < DD; kc += 32) {
    __syncthreads();
    {  // stage A rows (m-block)
      int mrow = m0 + sr; if (mrow > MM - 1) mrow = MM - 1;
      const unsigned short* src = Xq + (size_t)mrow * DD + kc + sk;
      v8s t0 = *(const v8s*)(src);
      v8s t1 = *(const v8s*)(src + 8);
      *(v8s*)&As[sr * LDB + sk]     = t0;
      *(v8s*)&As[sr * LDB + sk + 8] = t1;
    }
    {  // stage B rows (n-block)
      int nrow = n0 + sr; if (nrow > MM - 1) nrow = MM - 1;
      const unsigned short* src = Xq + (size_t)nrow * DD + kc + sk;
      v8s t0 = *(const v8s*)(src);
      v8s t1 = *(const v8s*)(src + 8);
      *(v8s*)&Bs[sr * LDB + sk]     = t0;
      *(v8s*)&Bs[sr * LDB + sk + 8] = t1;
    }
    __syncthreads();

    v8s a[4], b[4];
    #pragma unroll
    for (int i = 0; i < 4; ++i)
      a[i] = *(const v8s*)&As[(wr * 64 + i * 16 + frow) * LDB + quad * 8];
    #pragma unroll
    for (int j = 0; j < 4; ++j)
      b[j] = *(const v8s*)&Bs[(wc * 64 + j * 16 + frow) * LDB + quad * 8];
    #pragma unroll
    for (int i = 0; i < 4; ++i)
      #pragma unroll
      for (int j = 0; j < 4; ++j)
        acc[i][j] = __builtin_amdgcn_mfma_f32_16x16x32_bf16(a[i], b[j], acc[i][j], 0, 0, 0);
  }

  // epilogue: C layout col=lane&15, row=quad*4+reg  [m89-verified]
  #pragma unroll
  for (int j = 0; j < 4; ++j) {
    int n = n0 + wc * 64 + j * 16 + frow;
    if (n >= MM) continue;
    #pragma unroll
    for (int i = 0; i < 4; ++i) {
      #pragma unroll
      for (int r = 0; r < 4; ++r) {
        int m = m0 + wr * 64 + i * 16 + quad * 4 + r;
        if (m < MM) S[((size_t)q * MM + m) * MM + n] = acc[i][j][r];
      }
    }
  }
}

// ---------------------------------------------------------------------------
// K3 fused (round-13 = round-9 revert + single-reciprocal dba):
//   - 16 static 2-bit radix-ballot passes (no cnt, no branch — the codegen
//     shape that measured 64 VGPR / 43% occ / 238.6 µs). Rounds 10-12 showed
//     every early-exit/launch-bounds variant loses to this via registers or
//     spills.
//   - chunked batched f64 reductions (round 9, bit-identical sv).
//   - dba: x[e] = acc[e] * (1/denom) — <=1ulp, uniform per row, register-
//     neutral; deletes 7 serial f64 divide chains.
//   - XCD-chunked block->row map keeps each query's rows on one XCD.
// ---------------------------------------------------------------------------
__launch_bounds__(256)
__global__ void k_srdba(const float* __restrict__ Xs, const float* __restrict__ Q,
                        const float* __restrict__ S,
                        float* __restrict__ out_x, float* __restrict__ out_rt,
                        double* __restrict__ resd) {
  const int wv   = threadIdx.x >> 6;
  const int lane = threadIdx.x & 63;
  const int b    = blockIdx.x;
  const int cb   = (b & 7) * 1250 + (b >> 3);    // 10000 = 8*1250, bijective
  const int row  = cb * 4 + wv;                  // 400 % 4 == 0: no q-crossing
  const int q    = row / MM;
  const int m    = row - q * MM;
  const float* Xq = Xs + (size_t)q * MM * DD;
  const float* Sr = S  + (size_t)row * MM;

  // own descriptor, f32 storage (promotion to f64 at use is exact)
  float a[8];
  {
    const float* ar = Xq + (size_t)m * DD + lane * 8;
    float4 a0 = *(const float4*)(ar);
    float4 a1 = *(const float4*)(ar + 4);
    a[0]=a0.x; a[1]=a0.y; a[2]=a0.z; a[3]=a0.w;
    a[4]=a1.x; a[5]=a1.y; a[6]=a1.z; a[7]=a1.w;
  }

  // monotone u32 keys over the S row
  unsigned kv[7];
  #pragma unroll
  for (int s = 0; s < 7; ++s) {
    int n = lane + 64 * s;
    if (n < MM) {
      unsigned u = __float_as_uint(Sr[n]);
      kv[s] = u ^ ((u >> 31) ? 0xFFFFFFFFu : 0x80000000u);   // monotone map
    } else {
      kv[s] = 0u;                                            // below all real keys
    }
  }

  __shared__ double   sv[4][NS];
  __shared__ int      si[4][NS];
  __shared__ double   tv[4][KK];
  __shared__ int      ti[4][KK];
  __shared__ unsigned lv[4][64];
  __shared__ int      li[4][64];

  // ---- PHASE 1a: T = NS-th largest key; 2 bits per pass, 16 static passes ----
  unsigned prefix = 0u;
  #pragma unroll
  for (int bit = 30; bit >= 0; bit -= 2) {
    unsigned c1 = prefix | (1u << bit);
    unsigned c2 = prefix | (2u << bit);
    unsigned c3 = prefix | (3u << bit);
    int n1 = 0, n2 = 0, n3 = 0;
    #pragma unroll
    for (int s = 0; s < 7; ++s) {
      n1 += (int)__popcll(__ballot(kv[s] >= c1));
      n2 += (int)__popcll(__ballot(kv[s] >= c2));
      n3 += (int)__popcll(__ballot(kv[s] >= c3));
    }
    prefix = (n3 >= NS) ? c3 : (n2 >= NS) ? c2 : (n1 >= NS) ? c1 : prefix;
  }
  // prefix == T: the NS-th largest key (exact)

  // ---- PHASE 1b: ballot-compact entries >= T (C in [NS, 64], asc index) ----
  int base = 0;
  #pragma unroll
  for (int s = 0; s < 7; ++s) {
    bool p = (kv[s] >= prefix);
    unsigned long long mk = __ballot(p);
    if (p) {
      unsigned lo = (unsigned)(mk & 0xFFFFFFFFull);
      unsigned hi = (unsigned)(mk >> 32);
      int pos = base + (int)__builtin_amdgcn_mbcnt_hi(hi,
                          __builtin_amdgcn_mbcnt_lo(lo, 0u));
      if (pos < 64) { lv[wv][pos] = kv[s]; li[wv][pos] = lane + 64 * s; }
    }
    base += (int)__popcll(mk);
  }
  int C = (base < 64) ? base : 64;          // clamp (pathological ties only)
  __syncthreads();

  // ---- PHASE 1c: rank among C entries; si[rank] = index (lax.top_k order) ----
  if (lane < C) {
    unsigned v = lv[wv][lane]; int n = li[wv][lane];
    int rank = 0;
    for (int i = 0; i < C; ++i)
      rank += (lv[wv][i] > v) || (lv[wv][i] == v && li[wv][i] < n);
    if (rank < NS) si[wv][rank] = n;
  }
  __syncthreads();

  // ---- PHASE 2: refine dots; chunks of 5 with batched butterfly stages.
  //      Per-dot stage order identical -> bit-identical sv. ----
  #pragma unroll
  for (int c0 = 0; c0 < NS; c0 += 5) {
    double dp[5];
    #pragma unroll
    for (int t = 0; t < 5; ++t) {
      int n = si[wv][c0 + t];                  // uniform LDS broadcast
      const float* br = Xq + (size_t)n * DD + lane * 8;
      float4 b0 = *(const float4*)(br);
      float4 b1 = *(const float4*)(br + 4);
      dp[t] = (double)a[0]*(double)b0.x + (double)a[1]*(double)b0.y
            + (double)a[2]*(double)b0.z + (double)a[3]*(double)b0.w
            + (double)a[4]*(double)b1.x + (double)a[5]*(double)b1.y
            + (double)a[6]*(double)b1.z + (double)a[7]*(double)b1.w;
    }
    #pragma unroll
    for (int off = 32; off; off >>= 1) {
      #pragma unroll
      for (int t = 0; t < 5; ++t)
        dp[t] += __shfl_xor(dp[t], off);       // 5 independent shuffles/stage
    }
    if (lane == 0) {
      #pragma unroll
      for (int t = 0; t < 5; ++t) sv[wv][c0 + t] = dp[t];
    }
  }
  __syncthreads();

  // exact rank among the NS refined values (value desc, index asc — lax.top_k)
  if (lane < NS) {
    double v = sv[wv][lane]; int n = si[wv][lane];
    int rank = 0;
    #pragma unroll
    for (int i = 0; i < NS; ++i)
      rank += (sv[wv][i] > v) || (sv[wv][i] == v && si[wv][i] < n);
    if (rank < KK) { tv[wv][rank] = v; ti[wv][rank] = n; }
  }
  __syncthreads();

  // dba: top-10 rows just read by this wave -> L1/L2 hot. Same accumulation
  // order as round 9; single reciprocal replaces 8 divides (<=1ulp, uniform).
  double acc[8] = {0,0,0,0,0,0,0,0};
  double denom = 0.0;
  #pragma unroll
  for (int k = 0; k < KK; ++k) {
    double vv = tv[wv][k];
    double wk = (k == 0) ? 1.0 : 0.15 * vv;
    denom += wk;
    const float* gr = Xq + (size_t)ti[wv][k] * DD + lane * 8;
    float4 g0 = *(const float4*)(gr);
    float4 g1 = *(const float4*)(gr + 4);
    acc[0] += wk * (double)g0.x; acc[1] += wk * (double)g0.y;
    acc[2] += wk * (double)g0.z; acc[3] += wk * (double)g0.w;
    acc[4] += wk * (double)g1.x; acc[5] += wk * (double)g1.y;
    acc[6] += wk * (double)g1.z; acc[7] += wk * (double)g1.w;
  }
  const double inv = 1.0 / denom;
  double x[8];
  #pragma unroll
  for (int e = 0; e < 8; ++e) x[e] = acc[e] * inv;

  float* ox = out_x + (size_t)row * DD + lane * 8;
  *(float4*)(ox)     = make_float4((float)x[0], (float)x[1], (float)x[2], (float)x[3]);
  *(float4*)(ox + 4) = make_float4((float)x[4], (float)x[5], (float)x[6], (float)x[7]);

  const float* Qr = Q + (size_t)q * DD + lane * 8;
  float4 q0 = *(const float4*)(Qr);
  float4 q1 = *(const float4*)(Qr + 4);
  double pp = x[0]*(double)q0.x + x[1]*(double)q0.y + x[2]*(double)q0.z + x[3]*(double)q0.w
            + x[4]*(double)q1.x + x[5]*(double)q1.y + x[6]*(double)q1.z + x[7]*(double)q1.w;
  #pragma unroll
  for (int off = 32; off; off >>= 1) pp += __shfl_xor(pp, off);
  if (lane == 0) { resd[row] = pp; out_rt[row] = (float)pp; }
}

// ---------------------------------------------------------------------------
// OLD K2 (fallback if ws too small): f32 tile GEMM + fused top-16
// ---------------------------------------------------------------------------
#define TM 32
#define TN 128
#define KC 16
__launch_bounds__(256, 2)
__global__ void k_score_top16(const float* __restrict__ Xs, int* __restrict__ idx16) {
  __shared__ float As_[KC][TM];
  __shared__ float Bs_[KC][TN];
  __shared__ float Cs_[TM][408];
  const int q   = blockIdx.y;
  const int m0  = blockIdx.x * TM;
  const int tid = threadIdx.x;
  const int tr  = tid & 7;
  const int tc  = tid >> 3;
  const float* Xq = Xs + (size_t)q * MM * DD;
  for (int nt = 0; nt < 4; ++nt) {
    const int n0 = nt * TN;
    float acc[4][4] = {{0.f,0.f,0.f,0.f},{0.f,0.f,0.f,0.f},
                       {0.f,0.f,0.f,0.f},{0.f,0.f,0.f,0.f}};
    for (int kc = 0; kc < DD; kc += KC) {
      __syncthreads();
      { int r = tid >> 3; int cc = (tid & 7) * 2;
        int mrow = m0 + r; if (mrow > MM - 1) mrow = MM - 1;
        float2 a = *(const float2*)(Xq + (size_t)mrow * DD + kc + cc);
        As_[cc + 0][r] = a.x; As_[cc + 1][r] = a.y; }
      { int r = tid >> 1; int cc = (tid & 1) * 8;
        int nrow = n0 + r; if (nrow > MM - 1) nrow = MM - 1;
        const float* src = Xq + (size_t)nrow * DD + kc + cc;
        #pragma unroll
        for (int j = 0; j < 2; ++j) {
          float4 b = *(const float4*)(src + 4 * j);
          Bs_[cc + 4*j + 0][r] = b.x; Bs_[cc + 4*j + 1][r] = b.y;
          Bs_[cc + 4*j + 2][r] = b.z; Bs_[cc + 4*j + 3][r] = b.w; } }
      __syncthreads();
      #pragma unroll
      for (int k = 0; k < KC; ++k) {
        float4 a4 = *(const float4*)&As_[k][tr * 4];
        float4 b4 = *(const float4*)&Bs_[k][tc * 4];
        float av[4] = {a4.x, a4.y, a4.z, a4.w};
        float bw[4] = {b4.x, b4.y, b4.z, b4.w};
        #pragma unroll
        for (int i = 0; i < 4; ++i)
          #pragma unroll
          for (int j = 0; j < 4; ++j)
            acc[i][j] = fmaf(av[i], bw[j], acc[i][j]);
      }
    }
    #pragma unroll
    for (int i = 0; i < 4; ++i) {
      int r = tr * 4 + i;
      #pragma unroll
      for (int j = 0; j < 4; ++j) {
        int col = n0 + tc * 4 + j;
        if (col < MM) Cs_[r][col] = acc[i][j];
      }
    }
  }
  __syncthreads();
  const int lane = tid & 63;
  const int wv   = tid >> 6;
  for (int r = wv; r < TM; r += 4) {
    const int m = m0 + r;
    if (m >= MM) continue;
    float v[7]; int nn[7];
    #pragma unroll
    for (int s = 0; s < 7; ++s) {
      int n = lane + 64 * s;
      bool ok = (n < MM);
      v[s]  = ok ? Cs_[r][n] : -INFINITY;
      nn[s] = ok ? n : 0x7fffffff;
    }
    for (int t = 0; t < 16; ++t) {
      float bv = v[0]; int bn = nn[0];
      #pragma unroll
      for (int s = 1; s < 7; ++s)
        if (v[s] > bv || (v[s] == bv && nn[s] < bn)) { bv = v[s]; bn = nn[s]; }
      for (int off = 32; off; off >>= 1) {
        float ov = __shfl_xor(bv, off);
        int   on = __shfl_xor(bn, off);
        if (ov > bv || (ov == bv && on < bn)) { bv = ov; bn = on; }
      }
      if (lane == 0) idx16[((size_t)q * MM + m) * 16 + t] = bn;
      #pragma unroll
      for (int s = 0; s < 7; ++s)
        if (nn[s] == bn) v[s] = -INFINITY;
    }
  }
}

// ---------------------------------------------------------------------------
// OLD K3: refine (fallback path)
// ---------------------------------------------------------------------------
__global__ void k_refine(const float* __restrict__ Xs, const int* __restrict__ idxbuf,
                         int ns, double* __restrict__ valsd, int* __restrict__ idx10) {
  const int row  = blockIdx.x;           // q*MM + m
  const int q    = row / MM;
  const int m    = row - q * MM;
  const int lane = threadIdx.x;          // 64
  const float* Xq = Xs + (size_t)q * MM * DD;

  double a[8];
  {
    const float* ar = Xq + (size_t)m * DD + lane * 8;
    float4 a0 = *(const float4*)(ar);
    float4 a1 = *(const float4*)(ar + 4);
    a[0]=a0.x; a[1]=a0.y; a[2]=a0.z; a[3]=a0.w;
    a[4]=a1.x; a[5]=a1.y; a[6]=a1.z; a[7]=a1.w;
  }
  __shared__ double sv[24];
  __shared__ int    si[24];
  for (int j = 0; j < ns; ++j) {
    int n = idxbuf[(size_t)row * ns + j];
    const float* br = Xq + (size_t)n * DD + lane * 8;
    float4 b0 = *(const float4*)(br);
    float4 b1 = *(const float4*)(br + 4);
    double s = a[0]*(double)b0.x + a[1]*(double)b0.y + a[2]*(double)b0.z + a[3]*(double)b0.w
             + a[4]*(double)b1.x + a[5]*(double)b1.y + a[6]*(double)b1.z + a[7]*(double)b1.w;
    for (int off = 32; off; off >>= 1) s += __shfl_xor(s, off);
    if (lane == 0) { sv[j] = s; si[j] = n; }
  }
  __syncthreads();
  if (lane < ns) {
    double v = sv[lane]; int n = si[lane];
    int rank = 0;
    for (int i = 0; i < ns; ++i)
      if (sv[i] > v || (sv[i] == v && si[i] < n)) ++rank;
    if (rank < KK) {
      valsd[(size_t)row * KK + rank] = v;
      idx10[(size_t)row * KK + rank] = n;
    }
  }
}

// ---------------------------------------------------------------------------
// OLD K4: x_dba + res_top (fallback path)
// ---------------------------------------------------------------------------
__global__ void k_dba(const float* __restrict__ Xs, const float* __restrict__ Q,
                      const double* __restrict__ valsd, const int* __restrict__ idx10,
                      float* __restrict__ out_x, float* __restrict__ out_rt,
                      double* __restrict__ resd) {
  const int row = blockIdx.x;            // q*MM + m
  const int q   = row / MM;
  const int tid = threadIdx.x;           // 128
  const float* Xq = Xs + (size_t)q * MM * DD;

  double w[KK]; int id[KK]; double denom = 0.0;
  #pragma unroll
  for (int k = 0; k < KK; ++k) {
    double vv = valsd[(size_t)row * KK + k];
    w[k] = (k == 0) ? 1.0 : 0.15 * vv;
    denom += w[k];
    id[k] = idx10[(size_t)row * KK + k];
  }
  double acc0 = 0, acc1 = 0, acc2 = 0, acc3 = 0;
  #pragma unroll
  for (int k = 0; k < KK; ++k) {
    float4 g = *(const float4*)(Xq + (size_t)id[k] * DD + tid * 4);
    acc0 += w[k] * (double)g.x;
    acc1 += w[k] * (double)g.y;
    acc2 += w[k] * (double)g.z;
    acc3 += w[k] * (double)g.w;
  }
  double x0 = acc0 / denom, x1 = acc1 / denom, x2 = acc2 / denom, x3 = acc3 / denom;
  ((float4*)out_x)[(size_t)row * 128 + tid] =
      make_float4((float)x0, (float)x1, (float)x2, (float)x3);

  const float* Qr = Q + (size_t)q * DD + tid * 4;
  double p = x0 * (double)Qr[0] + x1 * (double)Qr[1] + x2 * (double)Qr[2] + x3 * (double)Qr[3];
  for (int off = 32; off; off >>= 1) p += __shfl_xor(p, off);
  __shared__ double ps[2];
  if ((tid & 63) == 0) ps[tid >> 6] = p;
  __syncthreads();
  if (tid == 0) {
    double rt = ps[0] + ps[1];
    resd[row]   = rt;
    out_rt[row] = (float)rt;
  }
}

// ---------------------------------------------------------------------------
// K5: stable descending argsort of res_top (f64) per query → pre, rerank_final
// ---------------------------------------------------------------------------
__global__ void k_sort(const double* __restrict__ resd, const int* __restrict__ ranks,
                       float* __restrict__ out_rr, float* __restrict__ out_pre) {
  const int q   = blockIdx.x;
  const int tid = threadIdx.x;           // 512
  __shared__ double sv[MM];
  if (tid < MM) sv[tid] = resd[(size_t)q * MM + tid];
  __syncthreads();
  if (tid < MM) {
    double v = sv[tid];
    int rank = 0;
    for (int j = 0; j < MM; ++j) {
      double u = sv[j];
      rank += (u > v) || (u == v && j < tid);
    }
    out_pre[(size_t)q * MM + rank] = (float)tid;
    out_rr [(size_t)q * MM + rank] = (float)ranks[tid * NQ + q];
  }
}

// ---------------------------------------------------------------------------
extern "C" void kernel_launch(void* const* d_in, const int* in_sizes, int n_in,
                              void* d_out, int out_size, void* d_ws, size_t ws_size,
                              hipStream_t stream) {
  const float* X     = (const float*)d_in[0];
  const float* Q     = (const float*)d_in[1];
  const int*   ranks = (const int*)d_in[2];

  float* out    = (float*)d_out;
  float* out_rr = out;                   // rerank_final [100][400]
  float* out_rt = out + 40000;           // res_top      [100][400]
  float* out_pr = out + 80000;           // pre          [100][400]
  float* out_x  = out + 120000;          // x_dba        [100][400][512]

  float* Xs = (float*)d_ws;

  if (ws_size >= NEED_NEW) {
    float*          S     = (float*)          ((char*)d_ws + NOFF_S);
    unsigned short* Xsb   = (unsigned short*) ((char*)d_ws + NOFF_XB);
    double*         resd  = (double*)         ((char*)d_ws + NOFF_RES);

    k_gather<<<dim3(20000),   dim3(256), 0, stream>>>(X, ranks, Xs, Xsb, 1);
    k_gemm  <<<dim3(16, 100), dim3(256), 0, stream>>>(Xsb, S);
    k_srdba <<<dim3(10000),   dim3(256), 0, stream>>>(Xs, Q, S, out_x, out_rt, resd);
    k_sort  <<<dim3(100),     dim3(512), 0, stream>>>(resd, ranks, out_rr, out_pr);
  } else {
    int*    idx16 = (int*)   ((char*)d_ws + OOFF_IDX16);
    double* valsd = (double*)((char*)d_ws + OOFF_VALSD);
    int*    idx10 = (int*)   ((char*)d_ws + OOFF_IDX10);
    double* resd  = (double*)((char*)d_ws + OOFF_RESD);

    k_gather     <<<dim3(20000),   dim3(256), 0, stream>>>(X, ranks, Xs, (unsigned short*)0, 0);
    k_score_top16<<<dim3(13, 100), dim3(256), 0, stream>>>(Xs, idx16);
    k_refine     <<<dim3(40000),   dim3(64),  0, stream>>>(Xs, idx16, 16, valsd, idx10);
    k_dba        <<<dim3(40000),   dim3(128), 0, stream>>>(Xs, Q, valsd, idx10, out_x, out_rt, resd);
    k_sort       <<<dim3(100),     dim3(512), 0, stream>>>(resd, ranks, out_rr, out_pr);
  }
}

// Round 14
// 469.437 us; speedup vs baseline: 1.0751x; 1.0751x over previous
//
#include <hip/hip_runtime.h>
#include <math.h>

#define NQ 100
#define MM 400
#define DD 512
#define KK 10
#define NS 20           // screened candidates per row (true top-10 must be subset)

typedef short v8s __attribute__((ext_vector_type(8)));   // 8 bf16 (4 VGPRs)
typedef float v4f __attribute__((ext_vector_type(4)));   // 4 f32 acc

// ---- NEW-path workspace byte offsets ----
#define NOFF_S     81920000UL
#define NOFF_XB   145920000UL
#define NOFF_IDX  186880000UL
#define NOFF_VALS 190080000UL
#define NOFF_I10  193280000UL
#define NOFF_RES  194880000UL
#define NEED_NEW  195200000UL

// ---- OLD-path (fallback) offsets ----
#define OOFF_IDX16 81920000UL
#define OOFF_VALSD 84480000UL
#define OOFF_IDX10 87680000UL
#define OOFF_RESD  89280000UL

static __device__ __forceinline__ unsigned short f2bf(float x) {
  unsigned u = __float_as_uint(x);
  unsigned r = (u + 0x7FFFu + ((u >> 16) & 1u)) >> 16;   // RNE; inputs have no NaN
  return (unsigned short)r;
}

// ---------------------------------------------------------------------------
// K1: gather Xs[q][m][:] = X[ranks[m][q]][:]  (f32) + bf16 copy for MFMA screen
// ---------------------------------------------------------------------------
__global__ void k_gather(const float* __restrict__ X, const int* __restrict__ ranks,
                         float* __restrict__ Xs, unsigned short* __restrict__ Xsb,
                         int make_bf) {
  int gid = blockIdx.x * 256 + threadIdx.x;        // 5,120,000 threads exactly
  int c4  = gid & 127;
  int row = gid >> 7;                              // q*MM + m
  int q   = row / MM;
  int m   = row - q * MM;
  int id  = ranks[m * NQ + q];
  float4 v = ((const float4*)X)[(size_t)id * 128 + c4];
  ((float4*)Xs)[(size_t)row * 128 + c4] = v;
  if (make_bf) {
    ushort4 h;
    h.x = f2bf(v.x); h.y = f2bf(v.y); h.z = f2bf(v.z); h.w = f2bf(v.w);
    ((ushort4*)Xsb)[(size_t)row * 128 + c4] = h;
  }
}

// ---------------------------------------------------------------------------
// K2: bf16 MFMA screening GEMM  S = Xs Xs^T per query, S materialized f32.
// ---------------------------------------------------------------------------
#define LDB 40
__launch_bounds__(256)
__global__ void k_gemm(const unsigned short* __restrict__ Xsb, float* __restrict__ S) {
  __shared__ unsigned short As[128 * LDB];
  __shared__ unsigned short Bs[128 * LDB];

  const int q    = blockIdx.y;
  const int mt   = blockIdx.x >> 2;
  const int nt   = blockIdx.x & 3;
  const int m0   = mt * 128, n0 = nt * 128;
  const int tid  = threadIdx.x;
  const int wave = tid >> 6, lane = tid & 63;
  const int wr   = wave >> 1, wc = wave & 1;       // wave origin in block tile
  const int frow = lane & 15, quad = lane >> 4;

  const unsigned short* Xq = Xsb + (size_t)q * MM * DD;

  v4f acc[4][4];
  #pragma unroll
  for (int i = 0; i < 4; ++i)
    #pragma unroll
    for (int j = 0; j < 4; ++j)
      acc[i][j] = (v4f){0.f, 0.f, 0.f, 0.f};

  const int sr = tid >> 1;                 // staging row 0..127
  const int sk = (tid & 1) * 16;           // staging k-half

  for (int kc = 0; kc < DD; kc += 32) {
    __syncthreads();
    {  // stage A rows (m-block)
      int mrow = m0 + sr; if (mrow > MM - 1) mrow = MM - 1;
      const unsigned short* src = Xq + (size_t)mrow * DD + kc + sk;
      v8s t0 = *(const v8s*)(src);
      v8s t1 = *(const v8s*)(src + 8);
      *(v8s*)&As[sr * LDB + sk]     = t0;
      *(v8s*)&As[sr * LDB + sk + 8] = t1;
    }
    {  // stage B rows (n-block)
      int nrow = n0 + sr; if (nrow > MM - 1) nrow = MM - 1;
      const unsigned short* src = Xq + (size_t)nrow * DD + kc + sk;
      v8s t0 = *(const v8s*)(src);
      v8s t1 = *(const v8s*)(src + 8);
      *(v8s*)&Bs[sr * LDB + sk]     = t0;
      *(v8s*)&Bs[sr * LDB + sk + 8] = t1;
    }
    __syncthreads();

    v8s a[4], b[4];
    #pragma unroll
    for (int i = 0; i < 4; ++i)
      a[i] = *(const v8s*)&As[(wr * 64 + i * 16 + frow) * LDB + quad * 8];
    #pragma unroll
    for (int j = 0; j < 4; ++j)
      b[j] = *(const v8s*)&Bs[(wc * 64 + j * 16 + frow) * LDB + quad * 8];
    #pragma unroll
    for (int i = 0; i < 4; ++i)
      #pragma unroll
      for (int j = 0; j < 4; ++j)
        acc[i][j] = __builtin_amdgcn_mfma_f32_16x16x32_bf16(a[i], b[j], acc[i][j], 0, 0, 0);
  }

  // epilogue: C layout col=lane&15, row=quad*4+reg  [m89-verified]
  #pragma unroll
  for (int j = 0; j < 4; ++j) {
    int n = n0 + wc * 64 + j * 16 + frow;
    if (n >= MM) continue;
    #pragma unroll
    for (int i = 0; i < 4; ++i) {
      #pragma unroll
      for (int r = 0; r < 4; ++r) {
        int m = m0 + wr * 64 + i * 16 + quad * 4 + r;
        if (m < MM) S[((size_t)q * MM + m) * MM + n] = acc[i][j][r];
      }
    }
  }
}

// ---------------------------------------------------------------------------
// K3 fused (round-14 = EXACT round-9 restore): 2-bit radix-ballot selection
// (16 static passes) + chunked batched f64 reductions + per-element divides.
// Rounds 10-13 established this source is a measured local optimum at the
// 64-VGPR allocation cliff (238.6 µs, 43% occ); every perturbation (dynamic
// break, launch-bounds force, single-reciprocal) tipped the allocator into
// 68 VGPR or spills and regressed. Do not perturb without -Rpass evidence.
// ---------------------------------------------------------------------------
__launch_bounds__(256)
__global__ void k_srdba(const float* __restrict__ Xs, const float* __restrict__ Q,
                        const float* __restrict__ S,
                        float* __restrict__ out_x, float* __restrict__ out_rt,
                        double* __restrict__ resd) {
  const int wv   = threadIdx.x >> 6;
  const int lane = threadIdx.x & 63;
  const int b    = blockIdx.x;
  const int cb   = (b & 7) * 1250 + (b >> 3);    // 10000 = 8*1250, bijective
  const int row  = cb * 4 + wv;                  // 400 % 4 == 0: no q-crossing
  const int q    = row / MM;
  const int m    = row - q * MM;
  const float* Xq = Xs + (size_t)q * MM * DD;
  const float* Sr = S  + (size_t)row * MM;

  // own descriptor, f32 storage (promotion to f64 at use is exact)
  float a[8];
  {
    const float* ar = Xq + (size_t)m * DD + lane * 8;
    float4 a0 = *(const float4*)(ar);
    float4 a1 = *(const float4*)(ar + 4);
    a[0]=a0.x; a[1]=a0.y; a[2]=a0.z; a[3]=a0.w;
    a[4]=a1.x; a[5]=a1.y; a[6]=a1.z; a[7]=a1.w;
  }

  // monotone u32 keys over the S row
  unsigned kv[7];
  #pragma unroll
  for (int s = 0; s < 7; ++s) {
    int n = lane + 64 * s;
    if (n < MM) {
      unsigned u = __float_as_uint(Sr[n]);
      kv[s] = u ^ ((u >> 31) ? 0xFFFFFFFFu : 0x80000000u);   // monotone map
    } else {
      kv[s] = 0u;                                            // below all real keys
    }
  }

  __shared__ double   sv[4][NS];
  __shared__ int      si[4][NS];
  __shared__ double   tv[4][KK];
  __shared__ int      ti[4][KK];
  __shared__ unsigned lv[4][64];
  __shared__ int      li[4][64];

  // ---- PHASE 1a: T = NS-th largest key; 2 bits per pass (16 serial passes,
  //      3 independent counts per pass == two binary-search steps) ----
  unsigned prefix = 0u;
  #pragma unroll
  for (int bit = 30; bit >= 0; bit -= 2) {
    unsigned c1 = prefix | (1u << bit);
    unsigned c2 = prefix | (2u << bit);
    unsigned c3 = prefix | (3u << bit);
    int n1 = 0, n2 = 0, n3 = 0;
    #pragma unroll
    for (int s = 0; s < 7; ++s) {
      n1 += (int)__popcll(__ballot(kv[s] >= c1));
      n2 += (int)__popcll(__ballot(kv[s] >= c2));
      n3 += (int)__popcll(__ballot(kv[s] >= c3));
    }
    prefix = (n3 >= NS) ? c3 : (n2 >= NS) ? c2 : (n1 >= NS) ? c1 : prefix;
  }
  // prefix == T: the NS-th largest key (exact)

  // ---- PHASE 1b: ballot-compact entries >= T (C in [NS, 64], asc index) ----
  int base = 0;
  #pragma unroll
  for (int s = 0; s < 7; ++s) {
    bool p = (kv[s] >= prefix);
    unsigned long long mk = __ballot(p);
    if (p) {
      unsigned lo = (unsigned)(mk & 0xFFFFFFFFull);
      unsigned hi = (unsigned)(mk >> 32);
      int pos = base + (int)__builtin_amdgcn_mbcnt_hi(hi,
                          __builtin_amdgcn_mbcnt_lo(lo, 0u));
      if (pos < 64) { lv[wv][pos] = kv[s]; li[wv][pos] = lane + 64 * s; }
    }
    base += (int)__popcll(mk);
  }
  int C = (base < 64) ? base : 64;          // clamp (pathological ties only)
  __syncthreads();

  // ---- PHASE 1c: rank among C entries; si[rank] = index (lax.top_k order) ----
  if (lane < C) {
    unsigned v = lv[wv][lane]; int n = li[wv][lane];
    int rank = 0;
    for (int i = 0; i < C; ++i)
      rank += (lv[wv][i] > v) || (lv[wv][i] == v && li[wv][i] < n);
    if (rank < NS) si[wv][rank] = n;
  }
  __syncthreads();

  // ---- PHASE 2: refine dots; chunks of 5 with BATCHED butterfly stages.
  //      Per-dot stage order identical to before -> bit-identical sv. ----
  #pragma unroll
  for (int c0 = 0; c0 < NS; c0 += 5) {
    double dp[5];
    #pragma unroll
    for (int t = 0; t < 5; ++t) {
      int n = si[wv][c0 + t];                  // uniform LDS broadcast
      const float* br = Xq + (size_t)n * DD + lane * 8;
      float4 b0 = *(const float4*)(br);
      float4 b1 = *(const float4*)(br + 4);
      dp[t] = (double)a[0]*(double)b0.x + (double)a[1]*(double)b0.y
            + (double)a[2]*(double)b0.z + (double)a[3]*(double)b0.w
            + (double)a[4]*(double)b1.x + (double)a[5]*(double)b1.y
            + (double)a[6]*(double)b1.z + (double)a[7]*(double)b1.w;
    }
    #pragma unroll
    for (int off = 32; off; off >>= 1) {
      #pragma unroll
      for (int t = 0; t < 5; ++t)
        dp[t] += __shfl_xor(dp[t], off);       // 5 independent shuffles/stage
    }
    if (lane == 0) {
      #pragma unroll
      for (int t = 0; t < 5; ++t) sv[wv][c0 + t] = dp[t];
    }
  }
  __syncthreads();

  // exact rank among the NS refined values (value desc, index asc — lax.top_k)
  if (lane < NS) {
    double v = sv[wv][lane]; int n = si[wv][lane];
    int rank = 0;
    #pragma unroll
    for (int i = 0; i < NS; ++i)
      rank += (sv[wv][i] > v) || (sv[wv][i] == v && si[wv][i] < n);
    if (rank < KK) { tv[wv][rank] = v; ti[wv][rank] = n; }
  }
  __syncthreads();

  // dba: top-10 rows just read by this wave -> L1/L2 hot. Same accumulation
  // order and /denom as round 8/9 (per-element divide — the reciprocal
  // variant costs +4 VGPR and loses the occupancy tier, round 13).
  double acc[8] = {0,0,0,0,0,0,0,0};
  double denom = 0.0;
  #pragma unroll
  for (int k = 0; k < KK; ++k) {
    double vv = tv[wv][k];
    double wk = (k == 0) ? 1.0 : 0.15 * vv;
    denom += wk;
    const float* gr = Xq + (size_t)ti[wv][k] * DD + lane * 8;
    float4 g0 = *(const float4*)(gr);
    float4 g1 = *(const float4*)(gr + 4);
    acc[0] += wk * (double)g0.x; acc[1] += wk * (double)g0.y;
    acc[2] += wk * (double)g0.z; acc[3] += wk * (double)g0.w;
    acc[4] += wk * (double)g1.x; acc[5] += wk * (double)g1.y;
    acc[6] += wk * (double)g1.z; acc[7] += wk * (double)g1.w;
  }
  double x[8];
  #pragma unroll
  for (int e = 0; e < 8; ++e) x[e] = acc[e] / denom;

  float* ox = out_x + (size_t)row * DD + lane * 8;
  *(float4*)(ox)     = make_float4((float)x[0], (float)x[1], (float)x[2], (float)x[3]);
  *(float4*)(ox + 4) = make_float4((float)x[4], (float)x[5], (float)x[6], (float)x[7]);

  const float* Qr = Q + (size_t)q * DD + lane * 8;
  float4 q0 = *(const float4*)(Qr);
  float4 q1 = *(const float4*)(Qr + 4);
  double pp = x[0]*(double)q0.x + x[1]*(double)q0.y + x[2]*(double)q0.z + x[3]*(double)q0.w
            + x[4]*(double)q1.x + x[5]*(double)q1.y + x[6]*(double)q1.z + x[7]*(double)q1.w;
  #pragma unroll
  for (int off = 32; off; off >>= 1) pp += __shfl_xor(pp, off);
  if (lane == 0) { resd[row] = pp; out_rt[row] = (float)pp; }
}

// ---------------------------------------------------------------------------
// OLD K2 (fallback if ws too small): f32 tile GEMM + fused top-16
// ---------------------------------------------------------------------------
#define TM 32
#define TN 128
#define KC 16
__launch_bounds__(256, 2)
__global__ void k_score_top16(const float* __restrict__ Xs, int* __restrict__ idx16) {
  __shared__ float As_[KC][TM];
  __shared__ float Bs_[KC][TN];
  __shared__ float Cs_[TM][408];
  const int q   = blockIdx.y;
  const int m0  = blockIdx.x * TM;
  const int tid = threadIdx.x;
  const int tr  = tid & 7;
  const int tc  = tid >> 3;
  const float* Xq = Xs + (size_t)q * MM * DD;
  for (int nt = 0; nt < 4; ++nt) {
    const int n0 = nt * TN;
    float acc[4][4] = {{0.f,0.f,0.f,0.f},{0.f,0.f,0.f,0.f},
                       {0.f,0.f,0.f,0.f},{0.f,0.f,0.f,0.f}};
    for (int kc = 0; kc < DD; kc += KC) {
      __syncthreads();
      { int r = tid >> 3; int cc = (tid & 7) * 2;
        int mrow = m0 + r; if (mrow > MM - 1) mrow = MM - 1;
        float2 a = *(const float2*)(Xq + (size_t)mrow * DD + kc + cc);
        As_[cc + 0][r] = a.x; As_[cc + 1][r] = a.y; }
      { int r = tid >> 1; int cc = (tid & 1) * 8;
        int nrow = n0 + r; if (nrow > MM - 1) nrow = MM - 1;
        const float* src = Xq + (size_t)nrow * DD + kc + cc;
        #pragma unroll
        for (int j = 0; j < 2; ++j) {
          float4 b = *(const float4*)(src + 4 * j);
          Bs_[cc + 4*j + 0][r] = b.x; Bs_[cc + 4*j + 1][r] = b.y;
          Bs_[cc + 4*j + 2][r] = b.z; Bs_[cc + 4*j + 3][r] = b.w; } }
      __syncthreads();
      #pragma unroll
      for (int k = 0; k < KC; ++k) {
        float4 a4 = *(const float4*)&As_[k][tr * 4];
        float4 b4 = *(const float4*)&Bs_[k][tc * 4];
        float av[4] = {a4.x, a4.y, a4.z, a4.w};
        float bw[4] = {b4.x, b4.y, b4.z, b4.w};
        #pragma unroll
        for (int i = 0; i < 4; ++i)
          #pragma unroll
          for (int j = 0; j < 4; ++j)
            acc[i][j] = fmaf(av[i], bw[j], acc[i][j]);
      }
    }
    #pragma unroll
    for (int i = 0; i < 4; ++i) {
      int r = tr * 4 + i;
      #pragma unroll
      for (int j = 0; j < 4; ++j) {
        int col = n0 + tc * 4 + j;
        if (col < MM) Cs_[r][col] = acc[i][j];
      }
    }
  }
  __syncthreads();
  const int lane = tid & 63;
  const int wv   = tid >> 6;
  for (int r = wv; r < TM; r += 4) {
    const int m = m0 + r;
    if (m >= MM) continue;
    float v[7]; int nn[7];
    #pragma unroll
    for (int s = 0; s < 7; ++s) {
      int n = lane + 64 * s;
      bool ok = (n < MM);
      v[s]  = ok ? Cs_[r][n] : -INFINITY;
      nn[s] = ok ? n : 0x7fffffff;
    }
    for (int t = 0; t < 16; ++t) {
      float bv = v[0]; int bn = nn[0];
      #pragma unroll
      for (int s = 1; s < 7; ++s)
        if (v[s] > bv || (v[s] == bv && nn[s] < bn)) { bv = v[s]; bn = nn[s]; }
      for (int off = 32; off; off >>= 1) {
        float ov = __shfl_xor(bv, off);
        int   on = __shfl_xor(bn, off);
        if (ov > bv || (ov == bv && on < bn)) { bv = ov; bn = on; }
      }
      if (lane == 0) idx16[((size_t)q * MM + m) * 16 + t] = bn;
      #pragma unroll
      for (int s = 0; s < 7; ++s)
        if (nn[s] == bn) v[s] = -INFINITY;
    }
  }
}

// ---------------------------------------------------------------------------
// OLD K3: refine (fallback path)
// ---------------------------------------------------------------------------
__global__ void k_refine(const float* __restrict__ Xs, const int* __restrict__ idxbuf,
                         int ns, double* __restrict__ valsd, int* __restrict__ idx10) {
  const int row  = blockIdx.x;           // q*MM + m
  const int q    = row / MM;
  const int m    = row - q * MM;
  const int lane = threadIdx.x;          // 64
  const float* Xq = Xs + (size_t)q * MM * DD;

  double a[8];
  {
    const float* ar = Xq + (size_t)m * DD + lane * 8;
    float4 a0 = *(const float4*)(ar);
    float4 a1 = *(const float4*)(ar + 4);
    a[0]=a0.x; a[1]=a0.y; a[2]=a0.z; a[3]=a0.w;
    a[4]=a1.x; a[5]=a1.y; a[6]=a1.z; a[7]=a1.w;
  }
  __shared__ double sv[24];
  __shared__ int    si[24];
  for (int j = 0; j < ns; ++j) {
    int n = idxbuf[(size_t)row * ns + j];
    const float* br = Xq + (size_t)n * DD + lane * 8;
    float4 b0 = *(const float4*)(br);
    float4 b1 = *(const float4*)(br + 4);
    double s = a[0]*(double)b0.x + a[1]*(double)b0.y + a[2]*(double)b0.z + a[3]*(double)b0.w
             + a[4]*(double)b1.x + a[5]*(double)b1.y + a[6]*(double)b1.z + a[7]*(double)b1.w;
    for (int off = 32; off; off >>= 1) s += __shfl_xor(s, off);
    if (lane == 0) { sv[j] = s; si[j] = n; }
  }
  __syncthreads();
  if (lane < ns) {
    double v = sv[lane]; int n = si[lane];
    int rank = 0;
    for (int i = 0; i < ns; ++i)
      if (sv[i] > v || (sv[i] == v && si[i] < n)) ++rank;
    if (rank < KK) {
      valsd[(size_t)row * KK + rank] = v;
      idx10[(size_t)row * KK + rank] = n;
    }
  }
}

// ---------------------------------------------------------------------------
// OLD K4: x_dba + res_top (fallback path)
// ---------------------------------------------------------------------------
__global__ void k_dba(const float* __restrict__ Xs, const float* __restrict__ Q,
                      const double* __restrict__ valsd, const int* __restrict__ idx10,
                      float* __restrict__ out_x, float* __restrict__ out_rt,
                      double* __restrict__ resd) {
  const int row = blockIdx.x;            // q*MM + m
  const int q   = row / MM;
  const int tid = threadIdx.x;           // 128
  const float* Xq = Xs + (size_t)q * MM * DD;

  double w[KK]; int id[KK]; double denom = 0.0;
  #pragma unroll
  for (int k = 0; k < KK; ++k) {
    double vv = valsd[(size_t)row * KK + k];
    w[k] = (k == 0) ? 1.0 : 0.15 * vv;
    denom += w[k];
    id[k] = idx10[(size_t)row * KK + k];
  }
  double acc0 = 0, acc1 = 0, acc2 = 0, acc3 = 0;
  #pragma unroll
  for (int k = 0; k < KK; ++k) {
    float4 g = *(const float4*)(Xq + (size_t)id[k] * DD + tid * 4);
    acc0 += w[k] * (double)g.x;
    acc1 += w[k] * (double)g.y;
    acc2 += w[k] * (double)g.z;
    acc3 += w[k] * (double)g.w;
  }
  double x0 = acc0 / denom, x1 = acc1 / denom, x2 = acc2 / denom, x3 = acc3 / denom;
  ((float4*)out_x)[(size_t)row * 128 + tid] =
      make_float4((float)x0, (float)x1, (float)x2, (float)x3);

  const float* Qr = Q + (size_t)q * DD + tid * 4;
  double p = x0 * (double)Qr[0] + x1 * (double)Qr[1] + x2 * (double)Qr[2] + x3 * (double)Qr[3];
  for (int off = 32; off; off >>= 1) p += __shfl_xor(p, off);
  __shared__ double ps[2];
  if ((tid & 63) == 0) ps[tid >> 6] = p;
  __syncthreads();
  if (tid == 0) {
    double rt = ps[0] + ps[1];
    resd[row]   = rt;
    out_rt[row] = (float)rt;
  }
}

// ---------------------------------------------------------------------------
// K5: stable descending argsort of res_top (f64) per query → pre, rerank_final
// ---------------------------------------------------------------------------
__global__ void k_sort(const double* __restrict__ resd, const int* __restrict__ ranks,
                       float* __restrict__ out_rr, float* __restrict__ out_pre) {
  const int q   = blockIdx.x;
  const int tid = threadIdx.x;           // 512
  __shared__ double sv[MM];
  if (tid < MM) sv[tid] = resd[(size_t)q * MM + tid];
  __syncthreads();
  if (tid < MM) {
    double v = sv[tid];
    int rank = 0;
    for (int j = 0; j < MM; ++j) {
      double u = sv[j];
      rank += (u > v) || (u == v && j < tid);
    }
    out_pre[(size_t)q * MM + rank] = (float)tid;
    out_rr [(size_t)q * MM + rank] = (float)ranks[tid * NQ + q];
  }
}

// ---------------------------------------------------------------------------
extern "C" void kernel_launch(void* const* d_in, const int* in_sizes, int n_in,
                              void* d_out, int out_size, void* d_ws, size_t ws_size,
                              hipStream_t stream) {
  const float* X     = (const float*)d_in[0];
  const float* Q     = (const float*)d_in[1];
  const int*   ranks = (const int*)d_in[2];

  float* out    = (float*)d_out;
  float* out_rr = out;                   // rerank_final [100][400]
  float* out_rt = out + 40000;           // res_top      [100][400]
  float* out_pr = out + 80000;           // pre          [100][400]
  float* out_x  = out + 120000;          // x_dba        [100][400][512]

  float* Xs = (float*)d_ws;

  if (ws_size >= NEED_NEW) {
    float*          S     = (float*)          ((char*)d_ws + NOFF_S);
    unsigned short* Xsb   = (unsigned short*) ((char*)d_ws + NOFF_XB);
    double*         resd  = (double*)         ((char*)d_ws + NOFF_RES);

    k_gather<<<dim3(20000),   dim3(256), 0, stream>>>(X, ranks, Xs, Xsb, 1);
    k_gemm  <<<dim3(16, 100), dim3(256), 0, stream>>>(Xsb, S);
    k_srdba <<<dim3(10000),   dim3(256), 0, stream>>>(Xs, Q, S, out_x, out_rt, resd);
    k_sort  <<<dim3(100),     dim3(512), 0, stream>>>(resd, ranks, out_rr, out_pr);
  } else {
    int*    idx16 = (int*)   ((char*)d_ws + OOFF_IDX16);
    double* valsd = (double*)((char*)d_ws + OOFF_VALSD);
    int*    idx10 = (int*)   ((char*)d_ws + OOFF_IDX10);
    double* resd  = (double*)((char*)d_ws + OOFF_RESD);

    k_gather     <<<dim3(20000),   dim3(256), 0, stream>>>(X, ranks, Xs, (unsigned short*)0, 0);
    k_score_top16<<<dim3(13, 100), dim3(256), 0, stream>>>(Xs, idx16);
    k_refine     <<<dim3(40000),   dim3(64),  0, stream>>>(Xs, idx16, 16, valsd, idx10);
    k_dba        <<<dim3(40000),   dim3(128), 0, stream>>>(Xs, Q, valsd, idx10, out_x, out_rt, resd);
    k_sort       <<<dim3(100),     dim3(512), 0, stream>>>(resd, ranks, out_rr, out_pr);
  }
}

// Round 15
// 465.678 us; speedup vs baseline: 1.0838x; 1.0081x over previous
//
#include <hip/hip_runtime.h>
#include <math.h>

#define NQ 100
#define MM 400
#define DD 512
#define KK 10
#define NS 20           // screened candidates per row (true top-10 must be subset)

typedef short v8s __attribute__((ext_vector_type(8)));   // 8 bf16 (4 VGPRs)
typedef float v4f __attribute__((ext_vector_type(4)));   // 4 f32 acc

// ---- NEW-path workspace byte offsets ----
#define NOFF_S     81920000UL
#define NOFF_XB   145920000UL
#define NOFF_IDX  186880000UL
#define NOFF_VALS 190080000UL
#define NOFF_I10  193280000UL
#define NOFF_RES  194880000UL
#define NEED_NEW  195200000UL

// ---- OLD-path (fallback) offsets ----
#define OOFF_IDX16 81920000UL
#define OOFF_VALSD 84480000UL
#define OOFF_IDX10 87680000UL
#define OOFF_RESD  89280000UL

static __device__ __forceinline__ unsigned short f2bf(float x) {
  unsigned u = __float_as_uint(x);
  unsigned r = (u + 0x7FFFu + ((u >> 16) & 1u)) >> 16;   // RNE; inputs have no NaN
  return (unsigned short)r;
}

// ---------------------------------------------------------------------------
// K1: gather Xs[q][m][:] = X[ranks[m][q]][:]  (f32) + bf16 copy for MFMA screen
// ---------------------------------------------------------------------------
__global__ void k_gather(const float* __restrict__ X, const int* __restrict__ ranks,
                         float* __restrict__ Xs, unsigned short* __restrict__ Xsb,
                         int make_bf) {
  int gid = blockIdx.x * 256 + threadIdx.x;        // 5,120,000 threads exactly
  int c4  = gid & 127;
  int row = gid >> 7;                              // q*MM + m
  int q   = row / MM;
  int m   = row - q * MM;
  int id  = ranks[m * NQ + q];
  float4 v = ((const float4*)X)[(size_t)id * 128 + c4];
  ((float4*)Xs)[(size_t)row * 128 + c4] = v;
  if (make_bf) {
    ushort4 h;
    h.x = f2bf(v.x); h.y = f2bf(v.y); h.z = f2bf(v.z); h.w = f2bf(v.w);
    ((ushort4*)Xsb)[(size_t)row * 128 + c4] = h;
  }
}

// ---------------------------------------------------------------------------
// K2 (round-15): bf16 MFMA screening GEMM with global_load_lds staging.
//   - LDS layout LINEAR [128][32] shorts (64B rows) — required: gload_lds
//     dest is wave-uniform base + lane*16B (padding breaks it, m104/m173).
//   - bank check: fragment ds_read_b128 start-bank = (16*row+4*quad)%32 ->
//     8 start classes x 8 lanes, every bank serviced exactly 8x — even, same
//     as the old padded layout. No conflict penalty from pad removal.
//   - staging per K-step: wave w issues 4 global_load_lds (2 A-chunks + 2
//     B-chunks, 1KB each: chunk c = rows 16c..16c+15 of the 64B k-slice).
//     Layout identity: LDS byte c*1024 + lane*16 == row(c*16+lane>>2)*64 +
//     (lane&3)*16 — matches fragment reads exactly.
//   - numerics identical (same bf16 values -> same MFMA).
// ---------------------------------------------------------------------------
__launch_bounds__(256)
__global__ void k_gemm(const unsigned short* __restrict__ Xsb, float* __restrict__ S) {
  __shared__ unsigned short As[128 * 32];
  __shared__ unsigned short Bs[128 * 32];

  const int q    = blockIdx.y;
  const int mt   = blockIdx.x >> 2;
  const int nt   = blockIdx.x & 3;
  const int m0   = mt * 128, n0 = nt * 128;
  const int tid  = threadIdx.x;
  const int wave = tid >> 6, lane = tid & 63;
  const int wr   = wave >> 1, wc = wave & 1;       // wave origin in block tile
  const int frow = lane & 15, quad = lane >> 4;

  const unsigned short* Xq = Xsb + (size_t)q * MM * DD;

  v4f acc[4][4];
  #pragma unroll
  for (int i = 0; i < 4; ++i)
    #pragma unroll
    for (int j = 0; j < 4; ++j)
      acc[i][j] = (v4f){0.f, 0.f, 0.f, 0.f};

  // staging geometry: chunk c covers rows 16c..16c+15; lane covers
  // row = 16c + (lane>>2), 16B piece (lane&3) of the 64B k-slice.
  const int srow = lane >> 2;            // 0..15 within chunk
  const int spc  = (lane & 3) * 8;       // shorts offset within 32-short slice
  const int ca   = wave * 2;             // this wave's A/B chunk base (0,2,4,6)

  for (int kc = 0; kc < DD; kc += 32) {
    __syncthreads();
    #pragma unroll
    for (int cc = 0; cc < 2; ++cc) {
      int c = ca + cc;
      {  // A chunk c
        int r = c * 16 + srow;
        int mrow = m0 + r; if (mrow > MM - 1) mrow = MM - 1;
        const unsigned short* src = Xq + (size_t)mrow * DD + kc + spc;
        __builtin_amdgcn_global_load_lds(
            (const __attribute__((address_space(1))) unsigned int*)src,
            (__attribute__((address_space(3))) unsigned int*)&As[c * 512],
            16, 0, 0);
      }
      {  // B chunk c
        int r = c * 16 + srow;
        int nrow = n0 + r; if (nrow > MM - 1) nrow = MM - 1;
        const unsigned short* src = Xq + (size_t)nrow * DD + kc + spc;
        __builtin_amdgcn_global_load_lds(
            (const __attribute__((address_space(1))) unsigned int*)src,
            (__attribute__((address_space(3))) unsigned int*)&Bs[c * 512],
            16, 0, 0);
      }
    }
    __syncthreads();

    v8s a[4], b[4];
    #pragma unroll
    for (int i = 0; i < 4; ++i)
      a[i] = *(const v8s*)&As[(wr * 64 + i * 16 + frow) * 32 + quad * 8];
    #pragma unroll
    for (int j = 0; j < 4; ++j)
      b[j] = *(const v8s*)&Bs[(wc * 64 + j * 16 + frow) * 32 + quad * 8];
    #pragma unroll
    for (int i = 0; i < 4; ++i)
      #pragma unroll
      for (int j = 0; j < 4; ++j)
        acc[i][j] = __builtin_amdgcn_mfma_f32_16x16x32_bf16(a[i], b[j], acc[i][j], 0, 0, 0);
  }

  // epilogue: C layout col=lane&15, row=quad*4+reg  [m89-verified]
  #pragma unroll
  for (int j = 0; j < 4; ++j) {
    int n = n0 + wc * 64 + j * 16 + frow;
    if (n >= MM) continue;
    #pragma unroll
    for (int i = 0; i < 4; ++i) {
      #pragma unroll
      for (int r = 0; r < 4; ++r) {
        int m = m0 + wr * 64 + i * 16 + quad * 4 + r;
        if (m < MM) S[((size_t)q * MM + m) * MM + n] = acc[i][j][r];
      }
    }
  }
}

// ---------------------------------------------------------------------------
// K3 fused (frozen round-9 optimum): 2-bit radix-ballot selection (16 static
// passes) + chunked batched f64 reductions + per-element divides.
// Rounds 10-13: every perturbation (dynamic break, launch-bounds force,
// single-reciprocal) tipped the allocator off the 64-VGPR cliff and regressed.
// DO NOT PERTURB.
// ---------------------------------------------------------------------------
__launch_bounds__(256)
__global__ void k_srdba(const float* __restrict__ Xs, const float* __restrict__ Q,
                        const float* __restrict__ S,
                        float* __restrict__ out_x, float* __restrict__ out_rt,
                        double* __restrict__ resd) {
  const int wv   = threadIdx.x >> 6;
  const int lane = threadIdx.x & 63;
  const int b    = blockIdx.x;
  const int cb   = (b & 7) * 1250 + (b >> 3);    // 10000 = 8*1250, bijective
  const int row  = cb * 4 + wv;                  // 400 % 4 == 0: no q-crossing
  const int q    = row / MM;
  const int m    = row - q * MM;
  const float* Xq = Xs + (size_t)q * MM * DD;
  const float* Sr = S  + (size_t)row * MM;

  // own descriptor, f32 storage (promotion to f64 at use is exact)
  float a[8];
  {
    const float* ar = Xq + (size_t)m * DD + lane * 8;
    float4 a0 = *(const float4*)(ar);
    float4 a1 = *(const float4*)(ar + 4);
    a[0]=a0.x; a[1]=a0.y; a[2]=a0.z; a[3]=a0.w;
    a[4]=a1.x; a[5]=a1.y; a[6]=a1.z; a[7]=a1.w;
  }

  // monotone u32 keys over the S row
  unsigned kv[7];
  #pragma unroll
  for (int s = 0; s < 7; ++s) {
    int n = lane + 64 * s;
    if (n < MM) {
      unsigned u = __float_as_uint(Sr[n]);
      kv[s] = u ^ ((u >> 31) ? 0xFFFFFFFFu : 0x80000000u);   // monotone map
    } else {
      kv[s] = 0u;                                            // below all real keys
    }
  }

  __shared__ double   sv[4][NS];
  __shared__ int      si[4][NS];
  __shared__ double   tv[4][KK];
  __shared__ int      ti[4][KK];
  __shared__ unsigned lv[4][64];
  __shared__ int      li[4][64];

  // ---- PHASE 1a: T = NS-th largest key; 2 bits per pass, 16 static passes ----
  unsigned prefix = 0u;
  #pragma unroll
  for (int bit = 30; bit >= 0; bit -= 2) {
    unsigned c1 = prefix | (1u << bit);
    unsigned c2 = prefix | (2u << bit);
    unsigned c3 = prefix | (3u << bit);
    int n1 = 0, n2 = 0, n3 = 0;
    #pragma unroll
    for (int s = 0; s < 7; ++s) {
      n1 += (int)__popcll(__ballot(kv[s] >= c1));
      n2 += (int)__popcll(__ballot(kv[s] >= c2));
      n3 += (int)__popcll(__ballot(kv[s] >= c3));
    }
    prefix = (n3 >= NS) ? c3 : (n2 >= NS) ? c2 : (n1 >= NS) ? c1 : prefix;
  }
  // prefix == T: the NS-th largest key (exact)

  // ---- PHASE 1b: ballot-compact entries >= T (C in [NS, 64], asc index) ----
  int base = 0;
  #pragma unroll
  for (int s = 0; s < 7; ++s) {
    bool p = (kv[s] >= prefix);
    unsigned long long mk = __ballot(p);
    if (p) {
      unsigned lo = (unsigned)(mk & 0xFFFFFFFFull);
      unsigned hi = (unsigned)(mk >> 32);
      int pos = base + (int)__builtin_amdgcn_mbcnt_hi(hi,
                          __builtin_amdgcn_mbcnt_lo(lo, 0u));
      if (pos < 64) { lv[wv][pos] = kv[s]; li[wv][pos] = lane + 64 * s; }
    }
    base += (int)__popcll(mk);
  }
  int C = (base < 64) ? base : 64;          // clamp (pathological ties only)
  __syncthreads();

  // ---- PHASE 1c: rank among C entries; si[rank] = index (lax.top_k order) ----
  if (lane < C) {
    unsigned v = lv[wv][lane]; int n = li[wv][lane];
    int rank = 0;
    for (int i = 0; i < C; ++i)
      rank += (lv[wv][i] > v) || (lv[wv][i] == v && li[wv][i] < n);
    if (rank < NS) si[wv][rank] = n;
  }
  __syncthreads();

  // ---- PHASE 2: refine dots; chunks of 5 with batched butterfly stages ----
  #pragma unroll
  for (int c0 = 0; c0 < NS; c0 += 5) {
    double dp[5];
    #pragma unroll
    for (int t = 0; t < 5; ++t) {
      int n = si[wv][c0 + t];                  // uniform LDS broadcast
      const float* br = Xq + (size_t)n * DD + lane * 8;
      float4 b0 = *(const float4*)(br);
      float4 b1 = *(const float4*)(br + 4);
      dp[t] = (double)a[0]*(double)b0.x + (double)a[1]*(double)b0.y
            + (double)a[2]*(double)b0.z + (double)a[3]*(double)b0.w
            + (double)a[4]*(double)b1.x + (double)a[5]*(double)b1.y
            + (double)a[6]*(double)b1.z + (double)a[7]*(double)b1.w;
    }
    #pragma unroll
    for (int off = 32; off; off >>= 1) {
      #pragma unroll
      for (int t = 0; t < 5; ++t)
        dp[t] += __shfl_xor(dp[t], off);       // 5 independent shuffles/stage
    }
    if (lane == 0) {
      #pragma unroll
      for (int t = 0; t < 5; ++t) sv[wv][c0 + t] = dp[t];
    }
  }
  __syncthreads();

  // exact rank among the NS refined values (value desc, index asc — lax.top_k)
  if (lane < NS) {
    double v = sv[wv][lane]; int n = si[wv][lane];
    int rank = 0;
    #pragma unroll
    for (int i = 0; i < NS; ++i)
      rank += (sv[wv][i] > v) || (sv[wv][i] == v && si[wv][i] < n);
    if (rank < KK) { tv[wv][rank] = v; ti[wv][rank] = n; }
  }
  __syncthreads();

  // dba: top-10 rows just read by this wave -> L1/L2 hot. Per-element divide
  // (reciprocal variant costs +4 VGPR and loses the occupancy tier, r13).
  double acc[8] = {0,0,0,0,0,0,0,0};
  double denom = 0.0;
  #pragma unroll
  for (int k = 0; k < KK; ++k) {
    double vv = tv[wv][k];
    double wk = (k == 0) ? 1.0 : 0.15 * vv;
    denom += wk;
    const float* gr = Xq + (size_t)ti[wv][k] * DD + lane * 8;
    float4 g0 = *(const float4*)(gr);
    float4 g1 = *(const float4*)(gr + 4);
    acc[0] += wk * (double)g0.x; acc[1] += wk * (double)g0.y;
    acc[2] += wk * (double)g0.z; acc[3] += wk * (double)g0.w;
    acc[4] += wk * (double)g1.x; acc[5] += wk * (double)g1.y;
    acc[6] += wk * (double)g1.z; acc[7] += wk * (double)g1.w;
  }
  double x[8];
  #pragma unroll
  for (int e = 0; e < 8; ++e) x[e] = acc[e] / denom;

  float* ox = out_x + (size_t)row * DD + lane * 8;
  *(float4*)(ox)     = make_float4((float)x[0], (float)x[1], (float)x[2], (float)x[3]);
  *(float4*)(ox + 4) = make_float4((float)x[4], (float)x[5], (float)x[6], (float)x[7]);

  const float* Qr = Q + (size_t)q * DD + lane * 8;
  float4 q0 = *(const float4*)(Qr);
  float4 q1 = *(const float4*)(Qr + 4);
  double pp = x[0]*(double)q0.x + x[1]*(double)q0.y + x[2]*(double)q0.z + x[3]*(double)q0.w
            + x[4]*(double)q1.x + x[5]*(double)q1.y + x[6]*(double)q1.z + x[7]*(double)q1.w;
  #pragma unroll
  for (int off = 32; off; off >>= 1) pp += __shfl_xor(pp, off);
  if (lane == 0) { resd[row] = pp; out_rt[row] = (float)pp; }
}

// ---------------------------------------------------------------------------
// OLD K2 (fallback if ws too small): f32 tile GEMM + fused top-16
// ---------------------------------------------------------------------------
#define TM 32
#define TN 128
#define KC 16
__launch_bounds__(256, 2)
__global__ void k_score_top16(const float* __restrict__ Xs, int* __restrict__ idx16) {
  __shared__ float As_[KC][TM];
  __shared__ float Bs_[KC][TN];
  __shared__ float Cs_[TM][408];
  const int q   = blockIdx.y;
  const int m0  = blockIdx.x * TM;
  const int tid = threadIdx.x;
  const int tr  = tid & 7;
  const int tc  = tid >> 3;
  const float* Xq = Xs + (size_t)q * MM * DD;
  for (int nt = 0; nt < 4; ++nt) {
    const int n0 = nt * TN;
    float acc[4][4] = {{0.f,0.f,0.f,0.f},{0.f,0.f,0.f,0.f},
                       {0.f,0.f,0.f,0.f},{0.f,0.f,0.f,0.f}};
    for (int kc = 0; kc < DD; kc += KC) {
      __syncthreads();
      { int r = tid >> 3; int cc = (tid & 7) * 2;
        int mrow = m0 + r; if (mrow > MM - 1) mrow = MM - 1;
        float2 a = *(const float2*)(Xq + (size_t)mrow * DD + kc + cc);
        As_[cc + 0][r] = a.x; As_[cc + 1][r] = a.y; }
      { int r = tid >> 1; int cc = (tid & 1) * 8;
        int nrow = n0 + r; if (nrow > MM - 1) nrow = MM - 1;
        const float* src = Xq + (size_t)nrow * DD + kc + cc;
        #pragma unroll
        for (int j = 0; j < 2; ++j) {
          float4 b = *(const float4*)(src + 4 * j);
          Bs_[cc + 4*j + 0][r] = b.x; Bs_[cc + 4*j + 1][r] = b.y;
          Bs_[cc + 4*j + 2][r] = b.z; Bs_[cc + 4*j + 3][r] = b.w; } }
      __syncthreads();
      #pragma unroll
      for (int k = 0; k < KC; ++k) {
        float4 a4 = *(const float4*)&As_[k][tr * 4];
        float4 b4 = *(const float4*)&Bs_[k][tc * 4];
        float av[4] = {a4.x, a4.y, a4.z, a4.w};
        float bw[4] = {b4.x, b4.y, b4.z, b4.w};
        #pragma unroll
        for (int i = 0; i < 4; ++i)
          #pragma unroll
          for (int j = 0; j < 4; ++j)
            acc[i][j] = fmaf(av[i], bw[j], acc[i][j]);
      }
    }
    #pragma unroll
    for (int i = 0; i < 4; ++i) {
      int r = tr * 4 + i;
      #pragma unroll
      for (int j = 0; j < 4; ++j) {
        int col = n0 + tc * 4 + j;
        if (col < MM) Cs_[r][col] = acc[i][j];
      }
    }
  }
  __syncthreads();
  const int lane = tid & 63;
  const int wv   = tid >> 6;
  for (int r = wv; r < TM; r += 4) {
    const int m = m0 + r;
    if (m >= MM) continue;
    float v[7]; int nn[7];
    #pragma unroll
    for (int s = 0; s < 7; ++s) {
      int n = lane + 64 * s;
      bool ok = (n < MM);
      v[s]  = ok ? Cs_[r][n] : -INFINITY;
      nn[s] = ok ? n : 0x7fffffff;
    }
    for (int t = 0; t < 16; ++t) {
      float bv = v[0]; int bn = nn[0];
      #pragma unroll
      for (int s = 1; s < 7; ++s)
        if (v[s] > bv || (v[s] == bv && nn[s] < bn)) { bv = v[s]; bn = nn[s]; }
      for (int off = 32; off; off >>= 1) {
        float ov = __shfl_xor(bv, off);
        int   on = __shfl_xor(bn, off);
        if (ov > bv || (ov == bv && on < bn)) { bv = ov; bn = on; }
      }
      if (lane == 0) idx16[((size_t)q * MM + m) * 16 + t] = bn;
      #pragma unroll
      for (int s = 0; s < 7; ++s)
        if (nn[s] == bn) v[s] = -INFINITY;
    }
  }
}

// ---------------------------------------------------------------------------
// OLD K3: refine (fallback path)
// ---------------------------------------------------------------------------
__global__ void k_refine(const float* __restrict__ Xs, const int* __restrict__ idxbuf,
                         int ns, double* __restrict__ valsd, int* __restrict__ idx10) {
  const int row  = blockIdx.x;           // q*MM + m
  const int q    = row / MM;
  const int m    = row - q * MM;
  const int lane = threadIdx.x;          // 64
  const float* Xq = Xs + (size_t)q * MM * DD;

  double a[8];
  {
    const float* ar = Xq + (size_t)m * DD + lane * 8;
    float4 a0 = *(const float4*)(ar);
    float4 a1 = *(const float4*)(ar + 4);
    a[0]=a0.x; a[1]=a0.y; a[2]=a0.z; a[3]=a0.w;
    a[4]=a1.x; a[5]=a1.y; a[6]=a1.z; a[7]=a1.w;
  }
  __shared__ double sv[24];
  __shared__ int    si[24];
  for (int j = 0; j < ns; ++j) {
    int n = idxbuf[(size_t)row * ns + j];
    const float* br = Xq + (size_t)n * DD + lane * 8;
    float4 b0 = *(const float4*)(br);
    float4 b1 = *(const float4*)(br + 4);
    double s = a[0]*(double)b0.x + a[1]*(double)b0.y + a[2]*(double)b0.z + a[3]*(double)b0.w
             + a[4]*(double)b1.x + a[5]*(double)b1.y + a[6]*(double)b1.z + a[7]*(double)b1.w;
    for (int off = 32; off; off >>= 1) s += __shfl_xor(s, off);
    if (lane == 0) { sv[j] = s; si[j] = n; }
  }
  __syncthreads();
  if (lane < ns) {
    double v = sv[lane]; int n = si[lane];
    int rank = 0;
    for (int i = 0; i < ns; ++i)
      if (sv[i] > v || (sv[i] == v && si[i] < n)) ++rank;
    if (rank < KK) {
      valsd[(size_t)row * KK + rank] = v;
      idx10[(size_t)row * KK + rank] = n;
    }
  }
}

// ---------------------------------------------------------------------------
// OLD K4: x_dba + res_top (fallback path)
// ---------------------------------------------------------------------------
__global__ void k_dba(const float* __restrict__ Xs, const float* __restrict__ Q,
                      const double* __restrict__ valsd, const int* __restrict__ idx10,
                      float* __restrict__ out_x, float* __restrict__ out_rt,
                      double* __restrict__ resd) {
  const int row = blockIdx.x;            // q*MM + m
  const int q   = row / MM;
  const int tid = threadIdx.x;           // 128
  const float* Xq = Xs + (size_t)q * MM * DD;

  double w[KK]; int id[KK]; double denom = 0.0;
  #pragma unroll
  for (int k = 0; k < KK; ++k) {
    double vv = valsd[(size_t)row * KK + k];
    w[k] = (k == 0) ? 1.0 : 0.15 * vv;
    denom += w[k];
    id[k] = idx10[(size_t)row * KK + k];
  }
  double acc0 = 0, acc1 = 0, acc2 = 0, acc3 = 0;
  #pragma unroll
  for (int k = 0; k < KK; ++k) {
    float4 g = *(const float4*)(Xq + (size_t)id[k] * DD + tid * 4);
    acc0 += w[k] * (double)g.x;
    acc1 += w[k] * (double)g.y;
    acc2 += w[k] * (double)g.z;
    acc3 += w[k] * (double)g.w;
  }
  double x0 = acc0 / denom, x1 = acc1 / denom, x2 = acc2 / denom, x3 = acc3 / denom;
  ((float4*)out_x)[(size_t)row * 128 + tid] =
      make_float4((float)x0, (float)x1, (float)x2, (float)x3);

  const float* Qr = Q + (size_t)q * DD + tid * 4;
  double p = x0 * (double)Qr[0] + x1 * (double)Qr[1] + x2 * (double)Qr[2] + x3 * (double)Qr[3];
  for (int off = 32; off; off >>= 1) p += __shfl_xor(p, off);
  __shared__ double ps[2];
  if ((tid & 63) == 0) ps[tid >> 6] = p;
  __syncthreads();
  if (tid == 0) {
    double rt = ps[0] + ps[1];
    resd[row]   = rt;
    out_rt[row] = (float)rt;
  }
}

// ---------------------------------------------------------------------------
// K5: stable descending argsort of res_top (f64) per query → pre, rerank_final
// ---------------------------------------------------------------------------
__global__ void k_sort(const double* __restrict__ resd, const int* __restrict__ ranks,
                       float* __restrict__ out_rr, float* __restrict__ out_pre) {
  const int q   = blockIdx.x;
  const int tid = threadIdx.x;           // 512
  __shared__ double sv[MM];
  if (tid < MM) sv[tid] = resd[(size_t)q * MM + tid];
  __syncthreads();
  if (tid < MM) {
    double v = sv[tid];
    int rank = 0;
    for (int j = 0; j < MM; ++j) {
      double u = sv[j];
      rank += (u > v) || (u == v && j < tid);
    }
    out_pre[(size_t)q * MM + rank] = (float)tid;
    out_rr [(size_t)q * MM + rank] = (float)ranks[tid * NQ + q];
  }
}

// ---------------------------------------------------------------------------
extern "C" void kernel_launch(void* const* d_in, const int* in_sizes, int n_in,
                              void* d_out, int out_size, void* d_ws, size_t ws_size,
                              hipStream_t stream) {
  const float* X     = (const float*)d_in[0];
  const float* Q     = (const float*)d_in[1];
  const int*   ranks = (const int*)d_in[2];

  float* out    = (float*)d_out;
  float* out_rr = out;                   // rerank_final [100][400]
  float* out_rt = out + 40000;           // res_top      [100][400]
  float* out_pr = out + 80000;           // pre          [100][400]
  float* out_x  = out + 120000;          // x_dba        [100][400][512]

  float* Xs = (float*)d_ws;

  if (ws_size >= NEED_NEW) {
    float*          S     = (float*)          ((char*)d_ws + NOFF_S);
    unsigned short* Xsb   = (unsigned short*) ((char*)d_ws + NOFF_XB);
    double*         resd  = (double*)         ((char*)d_ws + NOFF_RES);

    k_gather<<<dim3(20000),   dim3(256), 0, stream>>>(X, ranks, Xs, Xsb, 1);
    k_gemm  <<<dim3(16, 100), dim3(256), 0, stream>>>(Xsb, S);
    k_srdba <<<dim3(10000),   dim3(256), 0, stream>>>(Xs, Q, S, out_x, out_rt, resd);
    k_sort  <<<dim3(100),     dim3(512), 0, stream>>>(resd, ranks, out_rr, out_pr);
  } else {
    int*    idx16 = (int*)   ((char*)d_ws + OOFF_IDX16);
    double* valsd = (double*)((char*)d_ws + OOFF_VALSD);
    int*    idx10 = (int*)   ((char*)d_ws + OOFF_IDX10);
    double* resd  = (double*)((char*)d_ws + OOFF_RESD);

    k_gather     <<<dim3(20000),   dim3(256), 0, stream>>>(X, ranks, Xs, (unsigned short*)0, 0);
    k_score_top16<<<dim3(13, 100), dim3(256), 0, stream>>>(Xs, idx16);
    k_refine     <<<dim3(40000),   dim3(64),  0, stream>>>(Xs, idx16, 16, valsd, idx10);
    k_dba        <<<dim3(40000),   dim3(128), 0, stream>>>(Xs, Q, valsd, idx10, out_x, out_rt, resd);
    k_sort       <<<dim3(100),     dim3(512), 0, stream>>>(resd, ranks, out_rr, out_pr);
  }
}